// Round 4
// baseline (105.004 us; speedup 1.0000x reference)
//
#include <hip/hip_runtime.h>

#define NB   4
#define NSEQ 4096
#define DK   64
#define NTOK (NB * NSEQ)

#define QK_SCALE 1.2011224087864498f   // sqrt(log2(e))

typedef __attribute__((ext_vector_type(8))) short short8;
typedef __attribute__((ext_vector_type(4))) float f32x4;

__device__ __forceinline__ float fast_exp2(float x) {
#if __has_builtin(__builtin_amdgcn_exp2f)
    return __builtin_amdgcn_exp2f(x);
#else
    return exp2f(x);
#endif
}

__device__ __forceinline__ unsigned short bf16_rne(float f) {
    unsigned u = __float_as_uint(f);
    u += 0x7fffu + ((u >> 16) & 1u);
    return (unsigned short)(u >> 16);
}

__device__ __forceinline__ short8 u4_to_s8(uint4 u) {
    union { uint4 u; short8 s; } c; c.u = u; return c.s;
}

// ---------------------------------------------------------------------------
// Kernel A: Qs/Ks = (x.wq/wk)*QK_SCALE, Vt[b][d][n] = bf16(x@Wv^T+bv)
// 256 blocks x 512 threads; 64 tokens per block.
// ---------------------------------------------------------------------------
__global__ __launch_bounds__(512) void qkv_kernel(
    const float* __restrict__ x, const float* __restrict__ Wv,
    const float* __restrict__ bv, const float* __restrict__ wq,
    const float* __restrict__ wk,
    float* __restrict__ Qs, float* __restrict__ Ks, unsigned short* __restrict__ Vt)
{
    __shared__ float x_lds[64 * 68];
    __shared__ float wvt[64 * 68];        // wvt[d*68+e] = Wv[e*64+d]
    __shared__ float wqk[128];
    __shared__ float bvl[64];
    __shared__ unsigned short vt_lds[64 * 72];   // [e][tok]

    const int t = threadIdx.x;
    const int tok0 = blockIdx.x * 64;

    #pragma unroll
    for (int r = 0; r < 2; ++r) {
        int f = t + 512 * r;
        int row = f >> 4, c4 = f & 15;
        float4 v = ((const float4*)(x + (size_t)(tok0 + row) * DK))[c4];
        *(float4*)&x_lds[row * 68 + c4 * 4] = v;
    }
    #pragma unroll
    for (int r = 0; r < 2; ++r) {
        int f = t + 512 * r;
        int e = f >> 4, c4 = f & 15;
        float4 v = ((const float4*)(Wv + e * DK))[c4];
        wvt[(c4 * 4 + 0) * 68 + e] = v.x;
        wvt[(c4 * 4 + 1) * 68 + e] = v.y;
        wvt[(c4 * 4 + 2) * 68 + e] = v.z;
        wvt[(c4 * 4 + 3) * 68 + e] = v.w;
    }
    if (t < 64) { wqk[t * 2] = wq[t]; wqk[t * 2 + 1] = wk[t]; bvl[t] = bv[t]; }
    __syncthreads();

    const int tok = t >> 3, oc = t & 7;
    const int e0 = oc * 8;
    float acc[8];
    #pragma unroll
    for (int ee = 0; ee < 8; ++ee) acc[ee] = bvl[e0 + ee];

    for (int d = 0; d < DK; d += 4) {
        float4 x4 = *(const float4*)&x_lds[tok * 68 + d];
        const float xs[4] = {x4.x, x4.y, x4.z, x4.w};
        #pragma unroll
        for (int dd = 0; dd < 4; ++dd) {
            float xv = xs[dd];
            const float4* wrow = (const float4*)&wvt[(d + dd) * 68 + e0];
            float4 wa = wrow[0], wb = wrow[1];
            acc[0] += xv * wa.x; acc[1] += xv * wa.y;
            acc[2] += xv * wa.z; acc[3] += xv * wa.w;
            acc[4] += xv * wb.x; acc[5] += xv * wb.y;
            acc[6] += xv * wb.z; acc[7] += xv * wb.w;
        }
    }
    #pragma unroll
    for (int k = 0; k < 8; ++k)
        vt_lds[(e0 + k) * 72 + tok] = bf16_rne(acc[k]);

    if (t < 128) {
        const int tk = t & 63;
        const int sel = (t >= 64);
        float a = 0.f;
        for (int d = 0; d < DK; ++d)
            a += x_lds[tk * 68 + d] * wqk[d * 2 + sel];
        (sel ? Ks : Qs)[tok0 + tk] = a * QK_SCALE;
    }
    __syncthreads();

    const int bb = tok0 >> 12, n0 = tok0 & 4095;
    {
        int d = t >> 3, c = t & 7;
        uint4 v = *(const uint4*)((const char*)vt_lds + d * 144 + c * 16);
        *(uint4*)(Vt + (size_t)(bb * 64 + d) * 4096 + n0 + c * 8) = v;
    }
}

// ---------------------------------------------------------------------------
// Kernel B: MFMA attention + residual + layernorm.
// 256 blocks (b, 64-row i-tile) x 1024 threads (16 waves = 4/SIMD).
// Wave w: rgrp = w>>3 (32 rows), je = w&7 (512-j slice).
// Software-pipelined: B fragments (global, L2-resident Vt) and K (LDS) for
// iteration s+1 are loaded before iteration s's score math, so MFMA's
// vmcnt wait lands on loads issued ~400 VALU-cycles earlier.
// ---------------------------------------------------------------------------
extern __shared__ float smem[];

__global__ __launch_bounds__(1024, 4) void attn_kernel(
    const float* __restrict__ x,
    const float* __restrict__ Qsg, const float* __restrict__ Ksg,
    const unsigned short* __restrict__ Vt,
    const float* __restrict__ gamma, const float* __restrict__ beta,
    float* __restrict__ out)
{
    float* k_lds = smem;                       // 4096 floats
    float* red   = smem + 4096;                // 8 slots x 64 rows x stride 68
    float* dred  = smem + 4096 + 8 * 64 * 68;  // 8 x 64

    const int t    = threadIdx.x;
    const int b    = blockIdx.x >> 6;
    const int i0   = (blockIdx.x & 63) << 6;
    const int w    = t >> 6;
    const int lane = t & 63;
    const int rit  = lane & 15;
    const int q    = lane >> 4;
    const int rgrp = w >> 3;
    const int je   = w & 7;

    ((float4*)k_lds)[t] = ((const float4*)(Ksg + (size_t)b * 4096))[t];

    const float Qs0 = Qsg[b * 4096 + i0 + rgrp * 32 + rit];
    const float Qs1 = Qsg[b * 4096 + i0 + rgrp * 32 + 16 + rit];

    f32x4 acc[2][4] = {};
    f32x4 accd[2] = {};
    const short onebf = (short)0x3F80;
    const short8 vones = {onebf, onebf, onebf, onebf, onebf, onebf, onebf, onebf};

    const int jw = je * 512;
    const unsigned short* vb = Vt + (size_t)b * 64 * 4096 + (size_t)rit * 4096 + jw + q * 8;
    const float* kp = &k_lds[jw + q * 8];

    // ---- prologue: loads for s=0 (B from global; K after barrier)
    uint4 nb0 = *(const uint4*)(vb);
    uint4 nb1 = *(const uint4*)(vb + 16 * 4096);
    uint4 nb2 = *(const uint4*)(vb + 32 * 4096);
    uint4 nb3 = *(const uint4*)(vb + 48 * 4096);

    __syncthreads();   // k_lds ready
    float4 nka = *(const float4*)(kp);
    float4 nkb = *(const float4*)(kp + 4);

    #pragma unroll 2
    for (int s = 0; s < 16; ++s) {
        // consume previously-issued loads
        uint4 bu0 = nb0, bu1 = nb1, bu2 = nb2, bu3 = nb3;
        float4 ka = nka, kb = nkb;

        // ---- issue loads for s+1 (overlaps with score math below)
        if (s < 15) {
            const unsigned short* vn = vb + (s + 1) * 32;
            nb0 = *(const uint4*)(vn);
            nb1 = *(const uint4*)(vn + 16 * 4096);
            nb2 = *(const uint4*)(vn + 32 * 4096);
            nb3 = *(const uint4*)(vn + 48 * 4096);
            const float* kn = kp + (s + 1) * 32;
            nka = *(const float4*)(kn);
            nkb = *(const float4*)(kn + 4);
        }

        // ---- score math (A fragments, 2 row tiles)
        float kv[8] = {ka.x, ka.y, ka.z, ka.w, kb.x, kb.y, kb.z, kb.w};
        float w0[8], w1[8];
        #pragma unroll
        for (int jj = 0; jj < 8; ++jj) {
            float d0 = Qs0 - kv[jj];
            float g0 = fast_exp2(-d0 * d0);
            float p0 = __builtin_fmaf(g0, 3.2552083e-4f, 7.8125e-3f);
            p0 = __builtin_fmaf(g0, p0, 0.125f);
            w0[jj] = __builtin_fmaf(g0, p0, 1.0f);     // exp(exp(-(Q-K)^2)/8)
            float d1 = Qs1 - kv[jj];
            float g1 = fast_exp2(-d1 * d1);
            float p1 = __builtin_fmaf(g1, 3.2552083e-4f, 7.8125e-3f);
            p1 = __builtin_fmaf(g1, p1, 0.125f);
            w1[jj] = __builtin_fmaf(g1, p1, 1.0f);
        }
        uint4 au0, au1;
        au0.x = __builtin_amdgcn_perm(__float_as_uint(w0[1]), __float_as_uint(w0[0]), 0x07060302u);
        au0.y = __builtin_amdgcn_perm(__float_as_uint(w0[3]), __float_as_uint(w0[2]), 0x07060302u);
        au0.z = __builtin_amdgcn_perm(__float_as_uint(w0[5]), __float_as_uint(w0[4]), 0x07060302u);
        au0.w = __builtin_amdgcn_perm(__float_as_uint(w0[7]), __float_as_uint(w0[6]), 0x07060302u);
        au1.x = __builtin_amdgcn_perm(__float_as_uint(w1[1]), __float_as_uint(w1[0]), 0x07060302u);
        au1.y = __builtin_amdgcn_perm(__float_as_uint(w1[3]), __float_as_uint(w1[2]), 0x07060302u);
        au1.z = __builtin_amdgcn_perm(__float_as_uint(w1[5]), __float_as_uint(w1[4]), 0x07060302u);
        au1.w = __builtin_amdgcn_perm(__float_as_uint(w1[7]), __float_as_uint(w1[6]), 0x07060302u);
        short8 a0 = u4_to_s8(au0);
        short8 a1 = u4_to_s8(au1);

        short8 b0 = u4_to_s8(bu0), b1 = u4_to_s8(bu1);
        short8 b2 = u4_to_s8(bu2), b3 = u4_to_s8(bu3);
        acc[0][0] = __builtin_amdgcn_mfma_f32_16x16x32_bf16(a0, b0, acc[0][0], 0, 0, 0);
        acc[0][1] = __builtin_amdgcn_mfma_f32_16x16x32_bf16(a0, b1, acc[0][1], 0, 0, 0);
        acc[0][2] = __builtin_amdgcn_mfma_f32_16x16x32_bf16(a0, b2, acc[0][2], 0, 0, 0);
        acc[0][3] = __builtin_amdgcn_mfma_f32_16x16x32_bf16(a0, b3, acc[0][3], 0, 0, 0);
        acc[1][0] = __builtin_amdgcn_mfma_f32_16x16x32_bf16(a1, b0, acc[1][0], 0, 0, 0);
        acc[1][1] = __builtin_amdgcn_mfma_f32_16x16x32_bf16(a1, b1, acc[1][1], 0, 0, 0);
        acc[1][2] = __builtin_amdgcn_mfma_f32_16x16x32_bf16(a1, b2, acc[1][2], 0, 0, 0);
        acc[1][3] = __builtin_amdgcn_mfma_f32_16x16x32_bf16(a1, b3, acc[1][3], 0, 0, 0);
        accd[0]   = __builtin_amdgcn_mfma_f32_16x16x32_bf16(a0, vones, accd[0], 0, 0, 0);
        accd[1]   = __builtin_amdgcn_mfma_f32_16x16x32_bf16(a1, vones, accd[1], 0, 0, 0);
    }

    // ---- write this wave's partials (slot je); C/D layout: col=rit, row=q*4+rg
    #pragma unroll
    for (int rt = 0; rt < 2; ++rt)
        #pragma unroll
        for (int ct = 0; ct < 4; ++ct)
            #pragma unroll
            for (int rg = 0; rg < 4; ++rg)
                red[(size_t)je * (64 * 68) + (rgrp * 32 + rt * 16 + q * 4 + rg) * 68 + ct * 16 + rit]
                    = acc[rt][ct][rg];
    if (rit == 0) {
        #pragma unroll
        for (int rt = 0; rt < 2; ++rt)
            #pragma unroll
            for (int rg = 0; rg < 4; ++rg)
                dred[je * 64 + rgrp * 32 + rt * 16 + q * 4 + rg] = accd[rt][rg];
    }
    __syncthreads();

    // ---- block-wide combine + softmax divide + residual + layernorm
    const int row = t >> 4, cg = t & 15;
    float dsum = 0.f;
    #pragma unroll
    for (int sl = 0; sl < 8; ++sl) dsum += dred[sl * 64 + row];
    const float inv = 1.0f / dsum;
    const size_t rowg = (size_t)(b * 4096 + i0 + row);
    const float* xr = x + rowg * 64;

    float h[4], sm = 0.f, ss = 0.f;
    #pragma unroll
    for (int ct = 0; ct < 4; ++ct) {
        float num = 0.f;
        #pragma unroll
        for (int sl = 0; sl < 8; ++sl)
            num += red[(size_t)sl * (64 * 68) + row * 68 + ct * 16 + cg];
        h[ct] = num * inv + xr[ct * 16 + cg];
        sm += h[ct]; ss += h[ct] * h[ct];
    }
    #pragma unroll
    for (int m = 1; m < 16; m <<= 1) { sm += __shfl_xor(sm, m); ss += __shfl_xor(ss, m); }
    const float mu   = sm * 0.015625f;
    const float var  = ss * 0.015625f - mu * mu;
    const float rstd = rsqrtf(var + 1e-5f);

    float* orow = out + rowg * 64;
    #pragma unroll
    for (int ct = 0; ct < 4; ++ct)
        orow[ct * 16 + cg] = (h[ct] - mu) * rstd * gamma[ct * 16 + cg] + beta[ct * 16 + cg];
}

// ---------------------------------------------------------------------------
extern "C" void kernel_launch(void* const* d_in, const int* in_sizes, int n_in,
                              void* d_out, int out_size, void* d_ws, size_t ws_size,
                              hipStream_t stream)
{
    const float* x     = (const float*)d_in[0];
    const float* Wv    = (const float*)d_in[1];
    const float* bv    = (const float*)d_in[2];
    const float* wq    = (const float*)d_in[3];
    const float* wk    = (const float*)d_in[4];
    const float* gamma = (const float*)d_in[5];
    const float* beta  = (const float*)d_in[6];
    float* out = (float*)d_out;

    // workspace: Qs[16384] f32 | Ks[16384] f32 | Vt[4*64*4096] bf16  (~2.23 MB)
    float* Qs = (float*)d_ws;
    float* Ks = Qs + NTOK;
    unsigned short* Vt = (unsigned short*)(Ks + NTOK);

    const int attn_lds = 4096 * 4 + 8 * 64 * 68 * 4 + 8 * 64 * 4;
    hipFuncSetAttribute((const void*)attn_kernel,
                        hipFuncAttributeMaxDynamicSharedMemorySize, attn_lds);

    qkv_kernel<<<dim3(NTOK / 64), dim3(512), 0, stream>>>(x, Wv, bv, wq, wk, Qs, Ks, Vt);
    attn_kernel<<<dim3(NB * (NSEQ / 64)), dim3(1024), attn_lds, stream>>>(
        x, Qs, Ks, Vt, gamma, beta, out);
}

// Round 5
// 104.430 us; speedup vs baseline: 1.0055x; 1.0055x over previous
//
#include <hip/hip_runtime.h>

#define NB   4
#define NSEQ 4096
#define DK   64
#define NTOK (NB * NSEQ)

#define QK_SCALE 1.2011224087864498f   // sqrt(log2(e))

typedef __attribute__((ext_vector_type(8))) short short8;
typedef __attribute__((ext_vector_type(4))) float f32x4;

__device__ __forceinline__ float fast_exp2(float x) {
#if __has_builtin(__builtin_amdgcn_exp2f)
    return __builtin_amdgcn_exp2f(x);
#else
    return exp2f(x);
#endif
}

__device__ __forceinline__ unsigned short bf16_rne(float f) {
    unsigned u = __float_as_uint(f);
    u += 0x7fffu + ((u >> 16) & 1u);
    return (unsigned short)(u >> 16);
}

__device__ __forceinline__ short8 u4_to_s8(uint4 u) {
    union { uint4 u; short8 s; } c; c.u = u; return c.s;
}

// ---------------------------------------------------------------------------
// Kernel A: Qs/Ks = (x.wq/wk)*QK_SCALE, Vt[b][d][n] = bf16(x@Wv^T+bv)
// 256 blocks x 512 threads; 64 tokens per block.
// ---------------------------------------------------------------------------
__global__ __launch_bounds__(512) void qkv_kernel(
    const float* __restrict__ x, const float* __restrict__ Wv,
    const float* __restrict__ bv, const float* __restrict__ wq,
    const float* __restrict__ wk,
    float* __restrict__ Qs, float* __restrict__ Ks, unsigned short* __restrict__ Vt)
{
    __shared__ float x_lds[64 * 68];
    __shared__ float wvt[64 * 68];        // wvt[d*68+e] = Wv[e*64+d]
    __shared__ float wqk[128];
    __shared__ float bvl[64];
    __shared__ unsigned short vt_lds[64 * 72];   // [e][tok]

    const int t = threadIdx.x;
    const int tok0 = blockIdx.x * 64;

    #pragma unroll
    for (int r = 0; r < 2; ++r) {
        int f = t + 512 * r;
        int row = f >> 4, c4 = f & 15;
        float4 v = ((const float4*)(x + (size_t)(tok0 + row) * DK))[c4];
        *(float4*)&x_lds[row * 68 + c4 * 4] = v;
    }
    #pragma unroll
    for (int r = 0; r < 2; ++r) {
        int f = t + 512 * r;
        int e = f >> 4, c4 = f & 15;
        float4 v = ((const float4*)(Wv + e * DK))[c4];
        wvt[(c4 * 4 + 0) * 68 + e] = v.x;
        wvt[(c4 * 4 + 1) * 68 + e] = v.y;
        wvt[(c4 * 4 + 2) * 68 + e] = v.z;
        wvt[(c4 * 4 + 3) * 68 + e] = v.w;
    }
    if (t < 64) { wqk[t * 2] = wq[t]; wqk[t * 2 + 1] = wk[t]; bvl[t] = bv[t]; }
    __syncthreads();

    const int tok = t >> 3, oc = t & 7;
    const int e0 = oc * 8;
    float acc[8];
    #pragma unroll
    for (int ee = 0; ee < 8; ++ee) acc[ee] = bvl[e0 + ee];

    for (int d = 0; d < DK; d += 4) {
        float4 x4 = *(const float4*)&x_lds[tok * 68 + d];
        const float xs[4] = {x4.x, x4.y, x4.z, x4.w};
        #pragma unroll
        for (int dd = 0; dd < 4; ++dd) {
            float xv = xs[dd];
            const float4* wrow = (const float4*)&wvt[(d + dd) * 68 + e0];
            float4 wa = wrow[0], wb = wrow[1];
            acc[0] += xv * wa.x; acc[1] += xv * wa.y;
            acc[2] += xv * wa.z; acc[3] += xv * wa.w;
            acc[4] += xv * wb.x; acc[5] += xv * wb.y;
            acc[6] += xv * wb.z; acc[7] += xv * wb.w;
        }
    }
    #pragma unroll
    for (int k = 0; k < 8; ++k)
        vt_lds[(e0 + k) * 72 + tok] = bf16_rne(acc[k]);

    if (t < 128) {
        const int tk = t & 63;
        const int sel = (t >= 64);
        float a = 0.f;
        for (int d = 0; d < DK; ++d)
            a += x_lds[tk * 68 + d] * wqk[d * 2 + sel];
        (sel ? Ks : Qs)[tok0 + tk] = a * QK_SCALE;
    }
    __syncthreads();

    const int bb = tok0 >> 12, n0 = tok0 & 4095;
    {
        int d = t >> 3, c = t & 7;
        uint4 v = *(const uint4*)((const char*)vt_lds + d * 144 + c * 16);
        *(uint4*)(Vt + (size_t)(bb * 64 + d) * 4096 + n0 + c * 8) = v;
    }
}

// ---------------------------------------------------------------------------
// Kernel B: MFMA attention + residual + layernorm.
// 256 blocks (b, 64-row i-tile) x 1024 threads (16 waves = 4/SIMD).
// Wave w = je (0..15): 64 rows x 256-j slice. Each B-fragment load feeds
// FOUR row-tiles (halves V/L2 traffic vs 32-row waves). Denominator via
// MFMA-ones. Two-stage 8-slot LDS combine (je>=8 accumulates into je-8),
// then block-wide softmax divide + residual + layernorm.
// ---------------------------------------------------------------------------
extern __shared__ float smem[];

__global__ __launch_bounds__(1024, 4) void attn_kernel(
    const float* __restrict__ x,
    const float* __restrict__ Qsg, const float* __restrict__ Ksg,
    const unsigned short* __restrict__ Vt,
    const float* __restrict__ gamma, const float* __restrict__ beta,
    float* __restrict__ out)
{
    float* k_lds = smem;                       // 4096 floats (16 KB)
    float* red   = smem + 4096;                // 8 slots x 64 rows x stride 68 (139.3 KB)
    float* dred  = smem + 4096 + 8 * 64 * 68;  // 16 x 64 (4 KB)

    const int t    = threadIdx.x;
    const int b    = blockIdx.x >> 6;
    const int i0   = (blockIdx.x & 63) << 6;
    const int je   = t >> 6;          // wave id = j-slice 0..15
    const int lane = t & 63;
    const int rit  = lane & 15;
    const int q    = lane >> 4;

    ((float4*)k_lds)[t] = ((const float4*)(Ksg + (size_t)b * 4096))[t];

    float Qr[4];
    #pragma unroll
    for (int rt = 0; rt < 4; ++rt)
        Qr[rt] = Qsg[b * 4096 + i0 + rt * 16 + rit];

    f32x4 acc[4][4] = {};
    f32x4 accd[4] = {};
    const short onebf = (short)0x3F80;
    const short8 vones = {onebf, onebf, onebf, onebf, onebf, onebf, onebf, onebf};

    const int jw = je * 256;
    const unsigned short* vb = Vt + (size_t)b * 64 * 4096 + (size_t)rit * 4096 + jw + q * 8;
    const float* kp = &k_lds[jw + q * 8];

    __syncthreads();   // k_lds ready

    #pragma unroll 2
    for (int s = 0; s < 8; ++s) {
        // ---- B fragments: 4 d-tiles straight from global (L2-resident Vt)
        const unsigned short* vn = vb + s * 32;
        uint4 bu0 = *(const uint4*)(vn);
        uint4 bu1 = *(const uint4*)(vn + 16 * 4096);
        uint4 bu2 = *(const uint4*)(vn + 32 * 4096);
        uint4 bu3 = *(const uint4*)(vn + 48 * 4096);

        const float* kn = kp + s * 32;
        float4 ka = *(const float4*)(kn);
        float4 kb = *(const float4*)(kn + 4);
        float kv[8] = {ka.x, ka.y, ka.z, ka.w, kb.x, kb.y, kb.z, kb.w};

        short8 b0 = u4_to_s8(bu0), b1 = u4_to_s8(bu1);
        short8 b2 = u4_to_s8(bu2), b3 = u4_to_s8(bu3);

        // ---- 4 row-tiles share the B fragments
        #pragma unroll
        for (int rt = 0; rt < 4; ++rt) {
            float w0[8];
            #pragma unroll
            for (int jj = 0; jj < 8; ++jj) {
                float d0 = Qr[rt] - kv[jj];
                float g0 = fast_exp2(-d0 * d0);
                float p0 = __builtin_fmaf(g0, 3.2552083e-4f, 7.8125e-3f);
                p0 = __builtin_fmaf(g0, p0, 0.125f);
                w0[jj] = __builtin_fmaf(g0, p0, 1.0f);   // exp(exp(-(Q-K)^2)/8)
            }
            uint4 au;
            au.x = __builtin_amdgcn_perm(__float_as_uint(w0[1]), __float_as_uint(w0[0]), 0x07060302u);
            au.y = __builtin_amdgcn_perm(__float_as_uint(w0[3]), __float_as_uint(w0[2]), 0x07060302u);
            au.z = __builtin_amdgcn_perm(__float_as_uint(w0[5]), __float_as_uint(w0[4]), 0x07060302u);
            au.w = __builtin_amdgcn_perm(__float_as_uint(w0[7]), __float_as_uint(w0[6]), 0x07060302u);
            short8 a0 = u4_to_s8(au);

            acc[rt][0] = __builtin_amdgcn_mfma_f32_16x16x32_bf16(a0, b0, acc[rt][0], 0, 0, 0);
            acc[rt][1] = __builtin_amdgcn_mfma_f32_16x16x32_bf16(a0, b1, acc[rt][1], 0, 0, 0);
            acc[rt][2] = __builtin_amdgcn_mfma_f32_16x16x32_bf16(a0, b2, acc[rt][2], 0, 0, 0);
            acc[rt][3] = __builtin_amdgcn_mfma_f32_16x16x32_bf16(a0, b3, acc[rt][3], 0, 0, 0);
            accd[rt]   = __builtin_amdgcn_mfma_f32_16x16x32_bf16(a0, vones, accd[rt], 0, 0, 0);
        }
    }

    // ---- two-stage combine into 8 slots; C/D layout: col=rit, row=q*4+rg
    const int slot = je & 7;
    float* rbase = red + (size_t)slot * (64 * 68);
    if (je < 8) {
        #pragma unroll
        for (int rt = 0; rt < 4; ++rt)
            #pragma unroll
            for (int ct = 0; ct < 4; ++ct)
                #pragma unroll
                for (int rg = 0; rg < 4; ++rg)
                    rbase[(rt * 16 + q * 4 + rg) * 68 + ct * 16 + rit] = acc[rt][ct][rg];
    }
    if (rit == 0) {
        #pragma unroll
        for (int rt = 0; rt < 4; ++rt)
            #pragma unroll
            for (int rg = 0; rg < 4; ++rg)
                dred[je * 64 + rt * 16 + q * 4 + rg] = accd[rt][rg];
    }
    __syncthreads();
    if (je >= 8) {
        #pragma unroll
        for (int rt = 0; rt < 4; ++rt)
            #pragma unroll
            for (int ct = 0; ct < 4; ++ct)
                #pragma unroll
                for (int rg = 0; rg < 4; ++rg) {
                    int idx = (rt * 16 + q * 4 + rg) * 68 + ct * 16 + rit;
                    rbase[idx] += acc[rt][ct][rg];
                }
    }
    __syncthreads();

    // ---- block-wide combine + softmax divide + residual + layernorm
    const int row = t >> 4, cg = t & 15;
    float dsum = 0.f;
    #pragma unroll
    for (int sl = 0; sl < 16; ++sl) dsum += dred[sl * 64 + row];
    const float inv = 1.0f / dsum;
    const size_t rowg = (size_t)(b * 4096 + i0 + row);
    const float* xr = x + rowg * 64;

    float h[4], sm = 0.f, ss = 0.f;
    #pragma unroll
    for (int ct = 0; ct < 4; ++ct) {
        float num = 0.f;
        #pragma unroll
        for (int sl = 0; sl < 8; ++sl)
            num += red[(size_t)sl * (64 * 68) + row * 68 + ct * 16 + cg];
        h[ct] = num * inv + xr[ct * 16 + cg];
        sm += h[ct]; ss += h[ct] * h[ct];
    }
    #pragma unroll
    for (int m = 1; m < 16; m <<= 1) { sm += __shfl_xor(sm, m); ss += __shfl_xor(ss, m); }
    const float mu   = sm * 0.015625f;
    const float var  = ss * 0.015625f - mu * mu;
    const float rstd = rsqrtf(var + 1e-5f);

    float* orow = out + rowg * 64;
    #pragma unroll
    for (int ct = 0; ct < 4; ++ct)
        orow[ct * 16 + cg] = (h[ct] - mu) * rstd * gamma[ct * 16 + cg] + beta[ct * 16 + cg];
}

// ---------------------------------------------------------------------------
extern "C" void kernel_launch(void* const* d_in, const int* in_sizes, int n_in,
                              void* d_out, int out_size, void* d_ws, size_t ws_size,
                              hipStream_t stream)
{
    const float* x     = (const float*)d_in[0];
    const float* Wv    = (const float*)d_in[1];
    const float* bv    = (const float*)d_in[2];
    const float* wq    = (const float*)d_in[3];
    const float* wk    = (const float*)d_in[4];
    const float* gamma = (const float*)d_in[5];
    const float* beta  = (const float*)d_in[6];
    float* out = (float*)d_out;

    // workspace: Qs[16384] f32 | Ks[16384] f32 | Vt[4*64*4096] bf16  (~2.23 MB)
    float* Qs = (float*)d_ws;
    float* Ks = Qs + NTOK;
    unsigned short* Vt = (unsigned short*)(Ks + NTOK);

    // dynamic LDS: k 16384 + red 8*64*68*4 = 139264 + dred 16*64*4 = 4096 -> 159744 B
    const int attn_lds = 4096 * 4 + 8 * 64 * 68 * 4 + 16 * 64 * 4;
    hipFuncSetAttribute((const void*)attn_kernel,
                        hipFuncAttributeMaxDynamicSharedMemorySize, attn_lds);

    qkv_kernel<<<dim3(NTOK / 64), dim3(512), 0, stream>>>(x, Wv, bv, wq, wk, Qs, Ks, Vt);
    attn_kernel<<<dim3(NB * (NSEQ / 64)), dim3(1024), attn_lds, stream>>>(
        x, Qs, Ks, Vt, gamma, beta, out);
}